// Round 10
// baseline (126.754 us; speedup 1.0000x reference)
//
#include <hip/hip_runtime.h>
#include <math.h>

// B=4, C=64, H=W=128, O=64, K=3, pad=1, stride=1
// Round-10: revert to exact R7 components (last green). Single delta: phase 2 processes
// kk in PAIRS — both streams' params + 16 corner LDS reads issued together, then
// convert+MFMA per stream (latency overlap without R8's pipeline/struct machinery).
// ws: xb 8.39 MB + wtB + pgwB (~8.5 MB)

typedef __attribute__((ext_vector_type(8))) short short8;   // 8 bf16 (A/B frag)
typedef __attribute__((ext_vector_type(4))) float f32x4;    // C/D frag

#define BWP 584   // pgwB row stride (576+8)

__device__ __forceinline__ float b2f(unsigned short h) {
    union { unsigned u; float f; } v; v.u = ((unsigned)h) << 16; return v.f;
}
__device__ __forceinline__ unsigned short f2b(float f) {   // RNE
    union { float f; unsigned u; } v; v.f = f;
    unsigned r = v.u + 0x7FFFu + ((v.u >> 16) & 1u);
    return (unsigned short)(r >> 16);
}

// ---------------- K0: NCHW fp32 -> NHWC bf16 (exact R7) ----------------
__global__ __launch_bounds__(256) void k_nhwc(const float* __restrict__ x,
                                              unsigned short* __restrict__ xb) {
    __shared__ float tile[64][33];
    int bid = blockIdx.x;
    int b = bid >> 9, h = (bid >> 2) & 127, w0 = (bid & 3) * 32;
    int t = threadIdx.x;
    for (int idx = t; idx < 2048; idx += 256) {
        int c = idx >> 5, w = idx & 31;
        tile[c][w] = x[((b * 64 + c) * 128 + h) * 128 + w0 + w];
    }
    __syncthreads();
    {
        int wl = t >> 3, c0 = (t & 7) * 8;
        short8 v;
#pragma unroll
        for (int e = 0; e < 8; ++e) v[e] = (short)f2b(tile[c0 + e][wl]);
        *(short8*)&xb[(((size_t)b * 128 + h) * 128 + w0 + wl) * 64 + c0] = v;
    }
}

// ---------------- K1: pack weights to bf16 (exact R7) ----------------
__global__ __launch_bounds__(256) void k_pack_w(const float* __restrict__ weight,
                                                const float* __restrict__ pg_w,
                                                unsigned short* __restrict__ wtB,
                                                unsigned short* __restrict__ pgwB) {
    int idx = blockIdx.x * 256 + threadIdx.x;
    if (idx < 36864) {
        int c = idx & 63, o = (idx >> 6) & 63, kk = idx >> 12;
        wtB[idx] = f2b(weight[(o * 64 + c) * 9 + kk]);
    }
    int i2 = idx - 36864;
    if (i2 >= 0 && i2 < 32 * BWP) {
        int pp = i2 / BWP, k = i2 - pp * BWP;
        float v = 0.f;
        if (pp < 27 && k < 576) {
            int q = k >> 6, c = k & 63;
            v = pg_w[(pp * 64 + c) * 9 + q];
        }
        pgwB[i2] = f2b(v);
    }
}

// ---------------- K2: fused offset-conv + deformable conv ----------------
// 1024 blocks (b x 16 x 16), tile = 8x8 px. 256 threads = 4 waves.
__global__ __launch_bounds__(256, 3) void k_fused(const unsigned short* __restrict__ xb,
                                                  const unsigned short* __restrict__ pgwB,
                                                  const float* __restrict__ pg_b,
                                                  const unsigned short* __restrict__ wtB,
                                                  const float* __restrict__ bias,
                                                  float* __restrict__ out) {
    __shared__ unsigned short patch[182 * 64];   // 23.3 KB [pos=yy*14+xx][c ^ (pos&7)*8]
    __shared__ float P_s[27 * 65];               // 7.0 KB  [param][px]

    int bid = blockIdx.x;
    int b  = bid >> 8;
    int h0 = ((bid >> 4) & 15) * 8;
    int w0 = (bid & 15) * 8;
    int t = threadIdx.x;
    int base_y = h0 - 2, base_x = w0 - 2;
    const unsigned short* xbb = xb + (size_t)b * 16384 * 64;

    // ---- phase 0: stage patch from xb; 1456 b128 chunks, coalesced (exact R7) ----
    for (int i = t; i < 1456; i += 256) {
        int yy = i / 112;
        int r  = i - yy * 112;
        int xx = r >> 3;
        int c0 = (r & 7) * 8;
        int gy = base_y + yy, gx = base_x + xx;
        int pos = yy * 14 + xx;
        short8 v = (short8)0;
        if (((unsigned)gy < 128u) && ((unsigned)gx < 128u))
            v = *(const short8*)&xbb[(gy * 128 + gx) * 64 + c0];
        *(short8*)&patch[pos * 64 + (c0 ^ ((pos & 7) * 8))] = v;
    }
    __syncthreads();

    int l = t & 63, w = t >> 6;
    int quad = l >> 4, ln = l & 15;
    int px = w * 16 + ln;
    int py = px >> 3, pxx = px & 7;
    int hh = h0 + py, ww = w0 + pxx;

    // ---- phase 1: offset conv MFMA (exact R7) ----
    {
        f32x4 o0 = {0.f, 0.f, 0.f, 0.f}, o1 = {0.f, 0.f, 0.f, 0.f};
#pragma unroll
        for (int kb = 0; kb < 18; ++kb) {
            int q = kb >> 1;
            int kh = q / 3, kw = q - 3 * (q / 3);
            int k0 = kb * 32 + quad * 8;
            short8 b0 = *(const short8*)&pgwB[ln * BWP + k0];
            short8 b1 = *(const short8*)&pgwB[(16 + ln) * BWP + k0];
            int aoff = (py + kh + 1) * 14 + (pxx + kw + 1);
            int c0 = (kb & 1) * 32 + quad * 8;
            short8 af = *(const short8*)&patch[aoff * 64 + (c0 ^ ((aoff & 7) * 8))];
            o0 = __builtin_amdgcn_mfma_f32_16x16x32_bf16(af, b0, o0, 0, 0, 0);
            o1 = __builtin_amdgcn_mfma_f32_16x16x32_bf16(af, b1, o1, 0, 0, 0);
        }
#pragma unroll
        for (int tile = 0; tile < 2; ++tile) {
            int p = tile * 16 + ln;
            f32x4 a = tile ? o1 : o0;
            if (p < 27) {
                float bo = pg_b[p];
#pragma unroll
                for (int i = 0; i < 4; ++i) {
                    int wpx = w * 16 + quad * 4 + i;
                    float v = a[i] + bo;
                    if (p >= 18) v = 1.f / (1.f + expf(-v));
                    P_s[p * 65 + wpx] = v;
                }
            }
        }
    }
    __syncthreads();

    // ---- phase 2: two-stream interleaved sampling + main GEMM ----
    f32x4 acc[4];
#pragma unroll
    for (int nt = 0; nt < 4; ++nt) acc[nt] = (f32x4){0.f, 0.f, 0.f, 0.f};

    for (int kp = 0; kp < 4; ++kp) {
        const int kkA = 2 * kp, kkB = 2 * kp + 1;

        // ===== stream A: params + corner loads (R7 body, loads only) =====
        float wA00, wA01, wA10, wA11;
        short8 rA[2][4];
        {
            int ki = kkA / 3, kj = kkA - 3 * (kkA / 3);
            float dyv = P_s[(2 * kkA) * 65 + px];
            float dxv = P_s[(2 * kkA + 1) * 65 + px];
            float m   = P_s[(18 + kkA) * 65 + px];
            float ys = (float)(hh - 1 + ki) + dyv;
            float xs = (float)(ww - 1 + kj) + dxv;
            float y0f = floorf(ys), x0f = floorf(xs);
            int y0 = (int)y0f, x0 = (int)x0f;
            float ly = ys - y0f, lx = xs - x0f;
            float v0y = ((unsigned)y0 < 128u) ? 1.f : 0.f;
            float v1y = ((unsigned)(y0 + 1) < 128u) ? 1.f : 0.f;
            float v0x = ((unsigned)x0 < 128u) ? 1.f : 0.f;
            float v1x = ((unsigned)(x0 + 1) < 128u) ? 1.f : 0.f;
            wA00 = (1.f - ly) * (1.f - lx) * v0y * v0x * m;
            wA01 = (1.f - ly) * lx * v0y * v1x * m;
            wA10 = ly * (1.f - lx) * v1y * v0x * m;
            wA11 = ly * lx * v1y * v1x * m;
            int ly0 = y0 - base_y, lx0 = x0 - base_x;
            if (((unsigned)ly0 < 12u) && ((unsigned)lx0 < 12u)) {
                int pos = ly0 * 14 + lx0;
#pragma unroll
                for (int kb = 0; kb < 2; ++kb) {
                    int c0 = kb * 32 + quad * 8;
                    rA[kb][0] = *(const short8*)&patch[pos * 64 + (c0 ^ ((pos & 7) * 8))];
                    rA[kb][1] = *(const short8*)&patch[(pos + 1) * 64 + (c0 ^ (((pos + 1) & 7) * 8))];
                    rA[kb][2] = *(const short8*)&patch[(pos + 14) * 64 + (c0 ^ (((pos + 14) & 7) * 8))];
                    rA[kb][3] = *(const short8*)&patch[(pos + 15) * 64 + (c0 ^ (((pos + 15) & 7) * 8))];
                }
            } else {
                int y0c = min(max(y0, 0), 127), y1c = min(max(y0 + 1, 0), 127);
                int x0c = min(max(x0, 0), 127), x1c = min(max(x0 + 1, 0), 127);
                int base00 = (y0c * 128 + x0c) * 64;
                int dxo = (x1c - x0c) * 64, dyo = (y1c - y0c) * 8192;
#pragma unroll
                for (int kb = 0; kb < 2; ++kb) {
                    int c0 = kb * 32 + quad * 8;
                    rA[kb][0] = *(const short8*)&xbb[base00 + c0];
                    rA[kb][1] = *(const short8*)&xbb[base00 + dxo + c0];
                    rA[kb][2] = *(const short8*)&xbb[base00 + dyo + c0];
                    rA[kb][3] = *(const short8*)&xbb[base00 + dyo + dxo + c0];
                }
            }
        }

        // ===== stream B: params + corner loads =====
        float wB00, wB01, wB10, wB11;
        short8 rB[2][4];
        {
            int ki = kkB / 3, kj = kkB - 3 * (kkB / 3);
            float dyv = P_s[(2 * kkB) * 65 + px];
            float dxv = P_s[(2 * kkB + 1) * 65 + px];
            float m   = P_s[(18 + kkB) * 65 + px];
            float ys = (float)(hh - 1 + ki) + dyv;
            float xs = (float)(ww - 1 + kj) + dxv;
            float y0f = floorf(ys), x0f = floorf(xs);
            int y0 = (int)y0f, x0 = (int)x0f;
            float ly = ys - y0f, lx = xs - x0f;
            float v0y = ((unsigned)y0 < 128u) ? 1.f : 0.f;
            float v1y = ((unsigned)(y0 + 1) < 128u) ? 1.f : 0.f;
            float v0x = ((unsigned)x0 < 128u) ? 1.f : 0.f;
            float v1x = ((unsigned)(x0 + 1) < 128u) ? 1.f : 0.f;
            wB00 = (1.f - ly) * (1.f - lx) * v0y * v0x * m;
            wB01 = (1.f - ly) * lx * v0y * v1x * m;
            wB10 = ly * (1.f - lx) * v1y * v0x * m;
            wB11 = ly * lx * v1y * v1x * m;
            int ly0 = y0 - base_y, lx0 = x0 - base_x;
            if (((unsigned)ly0 < 12u) && ((unsigned)lx0 < 12u)) {
                int pos = ly0 * 14 + lx0;
#pragma unroll
                for (int kb = 0; kb < 2; ++kb) {
                    int c0 = kb * 32 + quad * 8;
                    rB[kb][0] = *(const short8*)&patch[pos * 64 + (c0 ^ ((pos & 7) * 8))];
                    rB[kb][1] = *(const short8*)&patch[(pos + 1) * 64 + (c0 ^ (((pos + 1) & 7) * 8))];
                    rB[kb][2] = *(const short8*)&patch[(pos + 14) * 64 + (c0 ^ (((pos + 14) & 7) * 8))];
                    rB[kb][3] = *(const short8*)&patch[(pos + 15) * 64 + (c0 ^ (((pos + 15) & 7) * 8))];
                }
            } else {
                int y0c = min(max(y0, 0), 127), y1c = min(max(y0 + 1, 0), 127);
                int x0c = min(max(x0, 0), 127), x1c = min(max(x0 + 1, 0), 127);
                int base00 = (y0c * 128 + x0c) * 64;
                int dxo = (x1c - x0c) * 64, dyo = (y1c - y0c) * 8192;
#pragma unroll
                for (int kb = 0; kb < 2; ++kb) {
                    int c0 = kb * 32 + quad * 8;
                    rB[kb][0] = *(const short8*)&xbb[base00 + c0];
                    rB[kb][1] = *(const short8*)&xbb[base00 + dxo + c0];
                    rB[kb][2] = *(const short8*)&xbb[base00 + dyo + c0];
                    rB[kb][3] = *(const short8*)&xbb[base00 + dyo + dxo + c0];
                }
            }
        }

        // ===== compute stream A: weights + convert + MFMA =====
        {
            const unsigned short* wk = wtB + kkA * 4096;
            short8 bfr[2][4];
#pragma unroll
            for (int kb = 0; kb < 2; ++kb)
#pragma unroll
                for (int nt = 0; nt < 4; ++nt)
                    bfr[kb][nt] = *(const short8*)&wk[(nt * 16 + ln) * 64 + kb * 32 + quad * 8];
            short8 af[2];
#pragma unroll
            for (int kb = 0; kb < 2; ++kb)
#pragma unroll
                for (int e = 0; e < 8; ++e) {
                    float v = wA00 * b2f((unsigned short)rA[kb][0][e]) + wA01 * b2f((unsigned short)rA[kb][1][e])
                            + wA10 * b2f((unsigned short)rA[kb][2][e]) + wA11 * b2f((unsigned short)rA[kb][3][e]);
                    af[kb][e] = (short)f2b(v);
                }
#pragma unroll
            for (int kb = 0; kb < 2; ++kb)
#pragma unroll
                for (int nt = 0; nt < 4; ++nt)
                    acc[nt] = __builtin_amdgcn_mfma_f32_16x16x32_bf16(af[kb], bfr[kb][nt], acc[nt], 0, 0, 0);
        }
        // ===== compute stream B =====
        {
            const unsigned short* wk = wtB + kkB * 4096;
            short8 bfr[2][4];
#pragma unroll
            for (int kb = 0; kb < 2; ++kb)
#pragma unroll
                for (int nt = 0; nt < 4; ++nt)
                    bfr[kb][nt] = *(const short8*)&wk[(nt * 16 + ln) * 64 + kb * 32 + quad * 8];
            short8 af[2];
#pragma unroll
            for (int kb = 0; kb < 2; ++kb)
#pragma unroll
                for (int e = 0; e < 8; ++e) {
                    float v = wB00 * b2f((unsigned short)rB[kb][0][e]) + wB01 * b2f((unsigned short)rB[kb][1][e])
                            + wB10 * b2f((unsigned short)rB[kb][2][e]) + wB11 * b2f((unsigned short)rB[kb][3][e]);
                    af[kb][e] = (short)f2b(v);
                }
#pragma unroll
            for (int kb = 0; kb < 2; ++kb)
#pragma unroll
                for (int nt = 0; nt < 4; ++nt)
                    acc[nt] = __builtin_amdgcn_mfma_f32_16x16x32_bf16(af[kb], bfr[kb][nt], acc[nt], 0, 0, 0);
        }
    }

    // ===== tail kk = 8 (exact R7 single body) =====
    {
        const int kk = 8;
        const unsigned short* wk = wtB + kk * 4096;
        short8 bfr[2][4];
#pragma unroll
        for (int kb = 0; kb < 2; ++kb)
#pragma unroll
            for (int nt = 0; nt < 4; ++nt)
                bfr[kb][nt] = *(const short8*)&wk[(nt * 16 + ln) * 64 + kb * 32 + quad * 8];

        int ki = 2, kj = 2;
        float dyv = P_s[(2 * kk) * 65 + px];
        float dxv = P_s[(2 * kk + 1) * 65 + px];
        float m   = P_s[(18 + kk) * 65 + px];
        float ys = (float)(hh - 1 + ki) + dyv;
        float xs = (float)(ww - 1 + kj) + dxv;
        float y0f = floorf(ys), x0f = floorf(xs);
        int y0 = (int)y0f, x0 = (int)x0f;
        float ly = ys - y0f, lx = xs - x0f;
        float v0y = ((unsigned)y0 < 128u) ? 1.f : 0.f;
        float v1y = ((unsigned)(y0 + 1) < 128u) ? 1.f : 0.f;
        float v0x = ((unsigned)x0 < 128u) ? 1.f : 0.f;
        float v1x = ((unsigned)(x0 + 1) < 128u) ? 1.f : 0.f;
        float w00 = (1.f - ly) * (1.f - lx) * v0y * v0x * m;
        float w01 = (1.f - ly) * lx * v0y * v1x * m;
        float w10 = ly * (1.f - lx) * v1y * v0x * m;
        float w11 = ly * lx * v1y * v1x * m;
        int ly0 = y0 - base_y, lx0 = x0 - base_x;
        short8 rT[2][4];
        if (((unsigned)ly0 < 12u) && ((unsigned)lx0 < 12u)) {
            int pos = ly0 * 14 + lx0;
#pragma unroll
            for (int kb = 0; kb < 2; ++kb) {
                int c0 = kb * 32 + quad * 8;
                rT[kb][0] = *(const short8*)&patch[pos * 64 + (c0 ^ ((pos & 7) * 8))];
                rT[kb][1] = *(const short8*)&patch[(pos + 1) * 64 + (c0 ^ (((pos + 1) & 7) * 8))];
                rT[kb][2] = *(const short8*)&patch[(pos + 14) * 64 + (c0 ^ (((pos + 14) & 7) * 8))];
                rT[kb][3] = *(const short8*)&patch[(pos + 15) * 64 + (c0 ^ (((pos + 15) & 7) * 8))];
            }
        } else {
            int y0c = min(max(y0, 0), 127), y1c = min(max(y0 + 1, 0), 127);
            int x0c = min(max(x0, 0), 127), x1c = min(max(x0 + 1, 0), 127);
            int base00 = (y0c * 128 + x0c) * 64;
            int dxo = (x1c - x0c) * 64, dyo = (y1c - y0c) * 8192;
#pragma unroll
            for (int kb = 0; kb < 2; ++kb) {
                int c0 = kb * 32 + quad * 8;
                rT[kb][0] = *(const short8*)&xbb[base00 + c0];
                rT[kb][1] = *(const short8*)&xbb[base00 + dxo + c0];
                rT[kb][2] = *(const short8*)&xbb[base00 + dyo + c0];
                rT[kb][3] = *(const short8*)&xbb[base00 + dyo + dxo + c0];
            }
        }
        short8 af[2];
#pragma unroll
        for (int kb = 0; kb < 2; ++kb)
#pragma unroll
            for (int e = 0; e < 8; ++e) {
                float v = w00 * b2f((unsigned short)rT[kb][0][e]) + w01 * b2f((unsigned short)rT[kb][1][e])
                        + w10 * b2f((unsigned short)rT[kb][2][e]) + w11 * b2f((unsigned short)rT[kb][3][e]);
                af[kb][e] = (short)f2b(v);
            }
#pragma unroll
        for (int kb = 0; kb < 2; ++kb)
#pragma unroll
            for (int nt = 0; nt < 4; ++nt)
                acc[nt] = __builtin_amdgcn_mfma_f32_16x16x32_bf16(af[kb], bfr[kb][nt], acc[nt], 0, 0, 0);
    }

    // ---- epilogue (exact R7) ----
    int px0 = w * 16 + quad * 4;
    int ehh = h0 + (px0 >> 3), eww = w0 + (px0 & 7);
#pragma unroll
    for (int nt = 0; nt < 4; ++nt) {
        int o = nt * 16 + ln;
        float bo = bias[o];
        float4 v;
        v.x = acc[nt][0] + bo; v.y = acc[nt][1] + bo;
        v.z = acc[nt][2] + bo; v.w = acc[nt][3] + bo;
        *(float4*)&out[((size_t)b * 64 + o) * 16384 + ehh * 128 + eww] = v;
    }
}

extern "C" void kernel_launch(void* const* d_in, const int* in_sizes, int n_in,
                              void* d_out, int out_size, void* d_ws, size_t ws_size,
                              hipStream_t stream) {
    const float* x      = (const float*)d_in[0];
    const float* weight = (const float*)d_in[1];
    const float* bias   = (const float*)d_in[2];
    const float* pg_w   = (const float*)d_in[3];
    const float* pg_b   = (const float*)d_in[4];
    float* out = (float*)d_out;

    unsigned short* xbB  = (unsigned short*)d_ws;        // 4*16384*64 bf16 (8.39 MB)
    unsigned short* wtB  = xbB + (size_t)4 * 16384 * 64; // 36,864 bf16
    unsigned short* pgwB = wtB + 36864;                  // 32*584 bf16   (~8.5 MB total)

    k_nhwc<<<2048, 256, 0, stream>>>(x, xbB);
    k_pack_w<<<218, 256, 0, stream>>>(weight, pg_w, wtB, pgwB);
    k_fused<<<1024, 256, 0, stream>>>(xbB, pgwB, pg_b, wtB, bias, out);
}

// Round 11
// 126.607 us; speedup vs baseline: 1.0012x; 1.0012x over previous
//
#include <hip/hip_runtime.h>
#include <math.h>

// B=4, C=64, H=W=128, O=64, K=3, pad=1, stride=1
// Round-11: K-split across 8 waves (512-thread blocks). Wave w: m-tile w&3, K-half w>>2.
//   phase 1: kb 0-8 / 9-17 partials, LDS-reduced before bias/sigmoid -> P_s
//   phase 2: kk 0-3 / 4-8 partial accumulators, LDS-reduced before epilogue
// Per-iteration bodies are verbatim R7/R10 (green). Doubles waves/CU, halves serial chain.
// ws: xb 8.39 MB + wtB + pgwB (~8.5 MB)

typedef __attribute__((ext_vector_type(8))) short short8;   // 8 bf16 (A/B frag)
typedef __attribute__((ext_vector_type(4))) float f32x4;    // C/D frag

#define BWP 584   // pgwB row stride (576+8)

__device__ __forceinline__ float b2f(unsigned short h) {
    union { unsigned u; float f; } v; v.u = ((unsigned)h) << 16; return v.f;
}
__device__ __forceinline__ unsigned short f2b(float f) {   // RNE
    union { float f; unsigned u; } v; v.f = f;
    unsigned r = v.u + 0x7FFFu + ((v.u >> 16) & 1u);
    return (unsigned short)(r >> 16);
}

// ---------------- K0: NCHW fp32 -> NHWC bf16 (exact R7/R10) ----------------
__global__ __launch_bounds__(256) void k_nhwc(const float* __restrict__ x,
                                              unsigned short* __restrict__ xb) {
    __shared__ float tile[64][33];
    int bid = blockIdx.x;
    int b = bid >> 9, h = (bid >> 2) & 127, w0 = (bid & 3) * 32;
    int t = threadIdx.x;
    for (int idx = t; idx < 2048; idx += 256) {
        int c = idx >> 5, w = idx & 31;
        tile[c][w] = x[((b * 64 + c) * 128 + h) * 128 + w0 + w];
    }
    __syncthreads();
    {
        int wl = t >> 3, c0 = (t & 7) * 8;
        short8 v;
#pragma unroll
        for (int e = 0; e < 8; ++e) v[e] = (short)f2b(tile[c0 + e][wl]);
        *(short8*)&xb[(((size_t)b * 128 + h) * 128 + w0 + wl) * 64 + c0] = v;
    }
}

// ---------------- K1: pack weights to bf16 (exact R7/R10) ----------------
__global__ __launch_bounds__(256) void k_pack_w(const float* __restrict__ weight,
                                                const float* __restrict__ pg_w,
                                                unsigned short* __restrict__ wtB,
                                                unsigned short* __restrict__ pgwB) {
    int idx = blockIdx.x * 256 + threadIdx.x;
    if (idx < 36864) {
        int c = idx & 63, o = (idx >> 6) & 63, kk = idx >> 12;
        wtB[idx] = f2b(weight[(o * 64 + c) * 9 + kk]);
    }
    int i2 = idx - 36864;
    if (i2 >= 0 && i2 < 32 * BWP) {
        int pp = i2 / BWP, k = i2 - pp * BWP;
        float v = 0.f;
        if (pp < 27 && k < 576) {
            int q = k >> 6, c = k & 63;
            v = pg_w[(pp * 64 + c) * 9 + q];
        }
        pgwB[i2] = f2b(v);
    }
}

// ---------------- K2: fused kernel, K-split over 8 waves ----------------
// 1024 blocks (b x 16 x 16), tile = 8x8 px. 512 threads = 8 waves.
__global__ __launch_bounds__(512, 8) void k_fused(const unsigned short* __restrict__ xb,
                                                  const unsigned short* __restrict__ pgwB,
                                                  const float* __restrict__ pg_b,
                                                  const unsigned short* __restrict__ wtB,
                                                  const float* __restrict__ bias,
                                                  float* __restrict__ out) {
    __shared__ unsigned short patch[182 * 64];   // 23.3 KB [pos=yy*14+xx][c ^ (pos&7)*8]
    __shared__ float P_s[27 * 65];               // 7.0 KB  [param][px]
    __shared__ float red[4096];                  // 16 KB   [reg][lane] reduction scratch

    int bid = blockIdx.x;
    int b  = bid >> 8;
    int h0 = ((bid >> 4) & 15) * 8;
    int w0 = (bid & 15) * 8;
    int t = threadIdx.x;
    int base_y = h0 - 2, base_x = w0 - 2;
    const unsigned short* xbb = xb + (size_t)b * 16384 * 64;

    // ---- phase 0: stage patch from xb (exact R7, 512-thread stride) ----
    for (int i = t; i < 1456; i += 512) {
        int yy = i / 112;
        int r  = i - yy * 112;
        int xx = r >> 3;
        int c0 = (r & 7) * 8;
        int gy = base_y + yy, gx = base_x + xx;
        int pos = yy * 14 + xx;
        short8 v = (short8)0;
        if (((unsigned)gy < 128u) && ((unsigned)gx < 128u))
            v = *(const short8*)&xbb[(gy * 128 + gx) * 64 + c0];
        *(short8*)&patch[pos * 64 + (c0 ^ ((pos & 7) * 8))] = v;
    }
    __syncthreads();

    int l = t & 63, w = t >> 6;        // w in 0..7
    int mt = w & 3, g = w >> 2;        // m-tile, K-half (wave-uniform)
    int quad = l >> 4, ln = l & 15;
    int px = mt * 16 + ln;
    int py = px >> 3, pxx = px & 7;
    int hh = h0 + py, ww = w0 + pxx;

    // ---- phase 1: offset conv MFMA partials (kb 0-8 for g=0, 9-17 for g=1) ----
    {
        f32x4 o0 = {0.f, 0.f, 0.f, 0.f}, o1 = {0.f, 0.f, 0.f, 0.f};
        if (g == 0) {
#pragma unroll
            for (int kb = 0; kb < 9; ++kb) {
                int q = kb >> 1;
                int kh = q / 3, kw = q - 3 * (q / 3);
                int k0 = kb * 32 + quad * 8;
                short8 b0 = *(const short8*)&pgwB[ln * BWP + k0];
                short8 b1 = *(const short8*)&pgwB[(16 + ln) * BWP + k0];
                int aoff = (py + kh + 1) * 14 + (pxx + kw + 1);
                int c0 = (kb & 1) * 32 + quad * 8;
                short8 af = *(const short8*)&patch[aoff * 64 + (c0 ^ ((aoff & 7) * 8))];
                o0 = __builtin_amdgcn_mfma_f32_16x16x32_bf16(af, b0, o0, 0, 0, 0);
                o1 = __builtin_amdgcn_mfma_f32_16x16x32_bf16(af, b1, o1, 0, 0, 0);
            }
        } else {
#pragma unroll
            for (int kb = 9; kb < 18; ++kb) {
                int q = kb >> 1;
                int kh = q / 3, kw = q - 3 * (q / 3);
                int k0 = kb * 32 + quad * 8;
                short8 b0 = *(const short8*)&pgwB[ln * BWP + k0];
                short8 b1 = *(const short8*)&pgwB[(16 + ln) * BWP + k0];
                int aoff = (py + kh + 1) * 14 + (pxx + kw + 1);
                int c0 = (kb & 1) * 32 + quad * 8;
                short8 af = *(const short8*)&patch[aoff * 64 + (c0 ^ ((aoff & 7) * 8))];
                o0 = __builtin_amdgcn_mfma_f32_16x16x32_bf16(af, b0, o0, 0, 0, 0);
                o1 = __builtin_amdgcn_mfma_f32_16x16x32_bf16(af, b1, o1, 0, 0, 0);
            }
            // write partials: red[(mt*8 + reg)*64 + l], reg = tile*4 + i  (conflict-free)
#pragma unroll
            for (int i = 0; i < 4; ++i) {
                red[(mt * 8 + 0 + i) * 64 + l] = o0[i];
                red[(mt * 8 + 4 + i) * 64 + l] = o1[i];
            }
        }
        __syncthreads();   // barrier 1: partials visible
        if (g == 0) {
#pragma unroll
            for (int i = 0; i < 4; ++i) {
                o0[i] += red[(mt * 8 + 0 + i) * 64 + l];
                o1[i] += red[(mt * 8 + 4 + i) * 64 + l];
            }
            // exact R7 phase-1 epilogue -> P_s
#pragma unroll
            for (int tile = 0; tile < 2; ++tile) {
                int p = tile * 16 + ln;
                f32x4 a = tile ? o1 : o0;
                if (p < 27) {
                    float bo = pg_b[p];
#pragma unroll
                    for (int i = 0; i < 4; ++i) {
                        int wpx = mt * 16 + quad * 4 + i;
                        float v = a[i] + bo;
                        if (p >= 18) v = 1.f / (1.f + expf(-v));
                        P_s[p * 65 + wpx] = v;
                    }
                }
            }
        }
    }
    __syncthreads();   // barrier 2: P_s complete (also: red reads done before reuse)

    // ---- phase 2: sampling + main GEMM partials (kk 0-3 for g=0, 4-8 for g=1) ----
    f32x4 acc[4];
#pragma unroll
    for (int nt = 0; nt < 4; ++nt) acc[nt] = (f32x4){0.f, 0.f, 0.f, 0.f};

    int kk_lo = g ? 4 : 0;
    int kk_hi = g ? 9 : 4;
    for (int kk = kk_lo; kk < kk_hi; ++kk) {
        // B fragments per-lane from global (L2-hot)
        const unsigned short* wk = wtB + kk * 4096;
        short8 bfr[2][4];
#pragma unroll
        for (int kb = 0; kb < 2; ++kb)
#pragma unroll
            for (int nt = 0; nt < 4; ++nt)
                bfr[kb][nt] = *(const short8*)&wk[(nt * 16 + ln) * 64 + kb * 32 + quad * 8];

        // bilinear params from LDS (exact R7 body)
        int ki = kk / 3, kj = kk - 3 * (kk / 3);
        float dyv = P_s[(2 * kk) * 65 + px];
        float dxv = P_s[(2 * kk + 1) * 65 + px];
        float m   = P_s[(18 + kk) * 65 + px];
        float ys = (float)(hh - 1 + ki) + dyv;
        float xs = (float)(ww - 1 + kj) + dxv;
        float y0f = floorf(ys), x0f = floorf(xs);
        int y0 = (int)y0f, x0 = (int)x0f;
        float ly = ys - y0f, lx = xs - x0f;
        float v0y = ((unsigned)y0 < 128u) ? 1.f : 0.f;
        float v1y = ((unsigned)(y0 + 1) < 128u) ? 1.f : 0.f;
        float v0x = ((unsigned)x0 < 128u) ? 1.f : 0.f;
        float v1x = ((unsigned)(x0 + 1) < 128u) ? 1.f : 0.f;
        float w00 = (1.f - ly) * (1.f - lx) * v0y * v0x * m;
        float w01 = (1.f - ly) * lx * v0y * v1x * m;
        float w10 = ly * (1.f - lx) * v1y * v0x * m;
        float w11 = ly * lx * v1y * v1x * m;
        int ly0 = y0 - base_y, lx0 = x0 - base_x;
        bool inp = ((unsigned)ly0 < 12u) && ((unsigned)lx0 < 12u);

        short8 r[2][4];
        if (inp) {
            int pos = ly0 * 14 + lx0;
#pragma unroll
            for (int kb = 0; kb < 2; ++kb) {
                int c0 = kb * 32 + quad * 8;
                r[kb][0] = *(const short8*)&patch[pos * 64 + (c0 ^ ((pos & 7) * 8))];
                r[kb][1] = *(const short8*)&patch[(pos + 1) * 64 + (c0 ^ (((pos + 1) & 7) * 8))];
                r[kb][2] = *(const short8*)&patch[(pos + 14) * 64 + (c0 ^ (((pos + 14) & 7) * 8))];
                r[kb][3] = *(const short8*)&patch[(pos + 15) * 64 + (c0 ^ (((pos + 15) & 7) * 8))];
            }
        } else {   // rare (|offset| >= 1): direct xb reads, clamped corners
            int y0c = min(max(y0, 0), 127), y1c = min(max(y0 + 1, 0), 127);
            int x0c = min(max(x0, 0), 127), x1c = min(max(x0 + 1, 0), 127);
            int base00 = (y0c * 128 + x0c) * 64;
            int dxo = (x1c - x0c) * 64, dyo = (y1c - y0c) * 8192;
#pragma unroll
            for (int kb = 0; kb < 2; ++kb) {
                int c0 = kb * 32 + quad * 8;
                r[kb][0] = *(const short8*)&xbb[base00 + c0];
                r[kb][1] = *(const short8*)&xbb[base00 + dxo + c0];
                r[kb][2] = *(const short8*)&xbb[base00 + dyo + c0];
                r[kb][3] = *(const short8*)&xbb[base00 + dyo + dxo + c0];
            }
        }

        short8 af[2];
#pragma unroll
        for (int kb = 0; kb < 2; ++kb)
#pragma unroll
            for (int e = 0; e < 8; ++e) {
                float v = w00 * b2f((unsigned short)r[kb][0][e]) + w01 * b2f((unsigned short)r[kb][1][e])
                        + w10 * b2f((unsigned short)r[kb][2][e]) + w11 * b2f((unsigned short)r[kb][3][e]);
                af[kb][e] = (short)f2b(v);
            }

#pragma unroll
        for (int kb = 0; kb < 2; ++kb)
#pragma unroll
            for (int nt = 0; nt < 4; ++nt)
                acc[nt] = __builtin_amdgcn_mfma_f32_16x16x32_bf16(af[kb], bfr[kb][nt], acc[nt], 0, 0, 0);
    }

    // ---- reduce partial accumulators: g=1 -> LDS, g=0 adds ----
    if (g == 1) {
#pragma unroll
        for (int nt = 0; nt < 4; ++nt)
#pragma unroll
            for (int i = 0; i < 4; ++i)
                red[(mt * 16 + nt * 4 + i) * 64 + l] = acc[nt][i];
    }
    __syncthreads();   // barrier 3
    if (g == 0) {
#pragma unroll
        for (int nt = 0; nt < 4; ++nt)
#pragma unroll
            for (int i = 0; i < 4; ++i)
                acc[nt][i] += red[(mt * 16 + nt * 4 + i) * 64 + l];

        // ---- epilogue (exact R7) ----
        int px0 = mt * 16 + quad * 4;
        int ehh = h0 + (px0 >> 3), eww = w0 + (px0 & 7);
#pragma unroll
        for (int nt = 0; nt < 4; ++nt) {
            int o = nt * 16 + ln;
            float bo = bias[o];
            float4 v;
            v.x = acc[nt][0] + bo; v.y = acc[nt][1] + bo;
            v.z = acc[nt][2] + bo; v.w = acc[nt][3] + bo;
            *(float4*)&out[((size_t)b * 64 + o) * 16384 + ehh * 128 + eww] = v;
        }
    }
}

extern "C" void kernel_launch(void* const* d_in, const int* in_sizes, int n_in,
                              void* d_out, int out_size, void* d_ws, size_t ws_size,
                              hipStream_t stream) {
    const float* x      = (const float*)d_in[0];
    const float* weight = (const float*)d_in[1];
    const float* bias   = (const float*)d_in[2];
    const float* pg_w   = (const float*)d_in[3];
    const float* pg_b   = (const float*)d_in[4];
    float* out = (float*)d_out;

    unsigned short* xbB  = (unsigned short*)d_ws;        // 4*16384*64 bf16 (8.39 MB)
    unsigned short* wtB  = xbB + (size_t)4 * 16384 * 64; // 36,864 bf16
    unsigned short* pgwB = wtB + 36864;                  // 32*584 bf16   (~8.5 MB total)

    k_nhwc<<<2048, 256, 0, stream>>>(x, xbB);
    k_pack_w<<<218, 256, 0, stream>>>(weight, pg_w, wtB, pgwB);
    k_fused<<<1024, 512, 0, stream>>>(xbB, pgwB, pg_b, wtB, bias, out);
}

// Round 12
// 104.848 us; speedup vs baseline: 1.2089x; 1.2075x over previous
//
#include <hip/hip_runtime.h>
#include <math.h>

// B=4, C=64, H=W=128, O=64, K=3, pad=1, stride=1
// Round-12: R7 structure (best green, 50.6us) + ONE delta: fragment-ordered weights.
//   wtF / pgwF are packed so a wave's B-fragment load = base + lane*16B (contiguous 1KB,
//   8 cache lines) instead of 128B-strided per-lane gathers (~32 lines/load). Theory:
//   k_fused is L1-line-bandwidth bound on B loads (occupancy-insensitive 50-54us across
//   R7/R8/R10/R11 falsified all latency-hiding approaches).
// ws: xb 8.39 MB + wtF 72KB + pgwF 36KB (~8.5 MB)

typedef __attribute__((ext_vector_type(8))) short short8;   // 8 bf16 (A/B frag)
typedef __attribute__((ext_vector_type(4))) float f32x4;    // C/D frag

__device__ __forceinline__ float b2f(unsigned short h) {
    union { unsigned u; float f; } v; v.u = ((unsigned)h) << 16; return v.f;
}
__device__ __forceinline__ unsigned short f2b(float f) {   // RNE
    union { float f; unsigned u; } v; v.f = f;
    unsigned r = v.u + 0x7FFFu + ((v.u >> 16) & 1u);
    return (unsigned short)(r >> 16);
}

// ---------------- K0: NCHW fp32 -> NHWC bf16 (exact R7) ----------------
__global__ __launch_bounds__(256) void k_nhwc(const float* __restrict__ x,
                                              unsigned short* __restrict__ xb) {
    __shared__ float tile[64][33];
    int bid = blockIdx.x;
    int b = bid >> 9, h = (bid >> 2) & 127, w0 = (bid & 3) * 32;
    int t = threadIdx.x;
    for (int idx = t; idx < 2048; idx += 256) {
        int c = idx >> 5, w = idx & 31;
        tile[c][w] = x[((b * 64 + c) * 128 + h) * 128 + w0 + w];
    }
    __syncthreads();
    {
        int wl = t >> 3, c0 = (t & 7) * 8;
        short8 v;
#pragma unroll
        for (int e = 0; e < 8; ++e) v[e] = (short)f2b(tile[c0 + e][wl]);
        *(short8*)&xb[(((size_t)b * 128 + h) * 128 + w0 + wl) * 64 + c0] = v;
    }
}

// ---------------- K1: pack weights to bf16, FRAGMENT order ----------------
// wtF [grp=((kk*2+kb)*4+nt)][l][e]  (72*512): weight[(o*64+c)*9+kk], o=nt*16+ln, c=kb*32+quad*8+e
// pgwF[grp=(kb*2+tile)][l][e]       (36*512): pg_w[(p*64+c)*9+q], p=tile*16+ln, k=kb*32+quad*8+e
__global__ __launch_bounds__(256) void k_pack_w(const float* __restrict__ weight,
                                                const float* __restrict__ pg_w,
                                                unsigned short* __restrict__ wtF,
                                                unsigned short* __restrict__ pgwF) {
    int idx = blockIdx.x * 256 + threadIdx.x;
    if (idx < 36864) {
        int e = idx & 7, l = (idx >> 3) & 63, grp = idx >> 9;   // grp 0..71
        int nt = grp & 3, kb = (grp >> 2) & 1, kk = grp >> 3;
        int ln = l & 15, quad = l >> 4;
        int o = nt * 16 + ln;
        int c = kb * 32 + quad * 8 + e;
        wtF[idx] = f2b(weight[(o * 64 + c) * 9 + kk]);
    }
    int i2 = idx - 36864;
    if (i2 >= 0 && i2 < 18432) {
        int e = i2 & 7, l = (i2 >> 3) & 63, grp = i2 >> 9;      // grp 0..35
        int tile = grp & 1, kb = grp >> 1;
        int ln = l & 15, quad = l >> 4;
        int p = tile * 16 + ln;
        int k = kb * 32 + quad * 8 + e;
        float v = 0.f;
        if (p < 27) {
            int q = k >> 6, c = k & 63;
            v = pg_w[(p * 64 + c) * 9 + q];
        }
        pgwF[i2] = f2b(v);
    }
}

// ---------------- K2: fused offset-conv + deformable conv (R7 body) ----------------
// 1024 blocks (b x 16 x 16), tile = 8x8 px. 256 threads = 4 waves.
__global__ __launch_bounds__(256, 4) void k_fused(const unsigned short* __restrict__ xb,
                                                  const unsigned short* __restrict__ pgwF,
                                                  const float* __restrict__ pg_b,
                                                  const unsigned short* __restrict__ wtF,
                                                  const float* __restrict__ bias,
                                                  float* __restrict__ out) {
    __shared__ unsigned short patch[182 * 64];   // 23.3 KB [pos=yy*14+xx][c ^ (pos&7)*8]
    __shared__ float P_s[27 * 65];               // 7.0 KB  [param][px]

    int bid = blockIdx.x;
    int b  = bid >> 8;
    int h0 = ((bid >> 4) & 15) * 8;
    int w0 = (bid & 15) * 8;
    int t = threadIdx.x;
    int base_y = h0 - 2, base_x = w0 - 2;
    const unsigned short* xbb = xb + (size_t)b * 16384 * 64;

    // ---- phase 0: stage patch from xb; 1456 b128 chunks, coalesced (exact R7) ----
    for (int i = t; i < 1456; i += 256) {
        int yy = i / 112;
        int r  = i - yy * 112;
        int xx = r >> 3;
        int c0 = (r & 7) * 8;
        int gy = base_y + yy, gx = base_x + xx;
        int pos = yy * 14 + xx;
        short8 v = (short8)0;
        if (((unsigned)gy < 128u) && ((unsigned)gx < 128u))
            v = *(const short8*)&xbb[(gy * 128 + gx) * 64 + c0];
        *(short8*)&patch[pos * 64 + (c0 ^ ((pos & 7) * 8))] = v;
    }
    __syncthreads();

    int l = t & 63, w = t >> 6;
    int quad = l >> 4, ln = l & 15;
    int px = w * 16 + ln;
    int py = px >> 3, pxx = px & 7;
    int hh = h0 + py, ww = w0 + pxx;

    // ---- phase 1: offset conv MFMA (M=64, N=32, K=576), B from pgwF coalesced ----
    {
        f32x4 o0 = {0.f, 0.f, 0.f, 0.f}, o1 = {0.f, 0.f, 0.f, 0.f};
#pragma unroll
        for (int kb = 0; kb < 18; ++kb) {
            int q = kb >> 1;
            int kh = q / 3, kw = q - 3 * (q / 3);
            short8 b0 = *(const short8*)&pgwF[(kb * 2 + 0) * 512 + l * 8];   // lane*16B
            short8 b1 = *(const short8*)&pgwF[(kb * 2 + 1) * 512 + l * 8];
            int aoff = (py + kh + 1) * 14 + (pxx + kw + 1);
            int c0 = (kb & 1) * 32 + quad * 8;
            short8 af = *(const short8*)&patch[aoff * 64 + (c0 ^ ((aoff & 7) * 8))];
            o0 = __builtin_amdgcn_mfma_f32_16x16x32_bf16(af, b0, o0, 0, 0, 0);
            o1 = __builtin_amdgcn_mfma_f32_16x16x32_bf16(af, b1, o1, 0, 0, 0);
        }
#pragma unroll
        for (int tile = 0; tile < 2; ++tile) {
            int p = tile * 16 + ln;
            f32x4 a = tile ? o1 : o0;
            if (p < 27) {
                float bo = pg_b[p];
#pragma unroll
                for (int i = 0; i < 4; ++i) {
                    int wpx = w * 16 + quad * 4 + i;
                    float v = a[i] + bo;
                    if (p >= 18) v = 1.f / (1.f + expf(-v));
                    P_s[p * 65 + wpx] = v;
                }
            }
        }
    }
    __syncthreads();

    // ---- phase 2: sampling + main GEMM (M=64,N=64,K=576), B from wtF coalesced ----
    f32x4 acc[4];
#pragma unroll
    for (int nt = 0; nt < 4; ++nt) acc[nt] = (f32x4){0.f, 0.f, 0.f, 0.f};

    for (int kk = 0; kk < 9; ++kk) {
        // B fragments: coalesced lane*16B loads (L1/L2-hot)
        short8 bfr[2][4];
#pragma unroll
        for (int kb = 0; kb < 2; ++kb)
#pragma unroll
            for (int nt = 0; nt < 4; ++nt)
                bfr[kb][nt] = *(const short8*)&wtF[((kk * 2 + kb) * 4 + nt) * 512 + l * 8];

        // bilinear params from LDS (exact R7 body)
        int ki = kk / 3, kj = kk - 3 * (kk / 3);
        float dyv = P_s[(2 * kk) * 65 + px];
        float dxv = P_s[(2 * kk + 1) * 65 + px];
        float m   = P_s[(18 + kk) * 65 + px];
        float ys = (float)(hh - 1 + ki) + dyv;
        float xs = (float)(ww - 1 + kj) + dxv;
        float y0f = floorf(ys), x0f = floorf(xs);
        int y0 = (int)y0f, x0 = (int)x0f;
        float ly = ys - y0f, lx = xs - x0f;
        float v0y = ((unsigned)y0 < 128u) ? 1.f : 0.f;
        float v1y = ((unsigned)(y0 + 1) < 128u) ? 1.f : 0.f;
        float v0x = ((unsigned)x0 < 128u) ? 1.f : 0.f;
        float v1x = ((unsigned)(x0 + 1) < 128u) ? 1.f : 0.f;
        float w00 = (1.f - ly) * (1.f - lx) * v0y * v0x * m;
        float w01 = (1.f - ly) * lx * v0y * v1x * m;
        float w10 = ly * (1.f - lx) * v1y * v0x * m;
        float w11 = ly * lx * v1y * v1x * m;
        int ly0 = y0 - base_y, lx0 = x0 - base_x;
        bool inp = ((unsigned)ly0 < 12u) && ((unsigned)lx0 < 12u);

        short8 r[2][4];
        if (inp) {
            int pos = ly0 * 14 + lx0;
#pragma unroll
            for (int kb = 0; kb < 2; ++kb) {
                int c0 = kb * 32 + quad * 8;
                r[kb][0] = *(const short8*)&patch[pos * 64 + (c0 ^ ((pos & 7) * 8))];
                r[kb][1] = *(const short8*)&patch[(pos + 1) * 64 + (c0 ^ (((pos + 1) & 7) * 8))];
                r[kb][2] = *(const short8*)&patch[(pos + 14) * 64 + (c0 ^ (((pos + 14) & 7) * 8))];
                r[kb][3] = *(const short8*)&patch[(pos + 15) * 64 + (c0 ^ (((pos + 15) & 7) * 8))];
            }
        } else {   // rare (|offset| >= 1): direct xb reads, clamped corners
            int y0c = min(max(y0, 0), 127), y1c = min(max(y0 + 1, 0), 127);
            int x0c = min(max(x0, 0), 127), x1c = min(max(x0 + 1, 0), 127);
            int base00 = (y0c * 128 + x0c) * 64;
            int dxo = (x1c - x0c) * 64, dyo = (y1c - y0c) * 8192;
#pragma unroll
            for (int kb = 0; kb < 2; ++kb) {
                int c0 = kb * 32 + quad * 8;
                r[kb][0] = *(const short8*)&xbb[base00 + c0];
                r[kb][1] = *(const short8*)&xbb[base00 + dxo + c0];
                r[kb][2] = *(const short8*)&xbb[base00 + dyo + c0];
                r[kb][3] = *(const short8*)&xbb[base00 + dyo + dxo + c0];
            }
        }

        short8 af[2];
#pragma unroll
        for (int kb = 0; kb < 2; ++kb)
#pragma unroll
            for (int e = 0; e < 8; ++e) {
                float v = w00 * b2f((unsigned short)r[kb][0][e]) + w01 * b2f((unsigned short)r[kb][1][e])
                        + w10 * b2f((unsigned short)r[kb][2][e]) + w11 * b2f((unsigned short)r[kb][3][e]);
                af[kb][e] = (short)f2b(v);
            }

#pragma unroll
        for (int kb = 0; kb < 2; ++kb)
#pragma unroll
            for (int nt = 0; nt < 4; ++nt)
                acc[nt] = __builtin_amdgcn_mfma_f32_16x16x32_bf16(af[kb], bfr[kb][nt], acc[nt], 0, 0, 0);
    }

    // ---- epilogue (exact R7) ----
    int px0 = w * 16 + quad * 4;
    int ehh = h0 + (px0 >> 3), eww = w0 + (px0 & 7);
#pragma unroll
    for (int nt = 0; nt < 4; ++nt) {
        int o = nt * 16 + ln;
        float bo = bias[o];
        float4 v;
        v.x = acc[nt][0] + bo; v.y = acc[nt][1] + bo;
        v.z = acc[nt][2] + bo; v.w = acc[nt][3] + bo;
        *(float4*)&out[((size_t)b * 64 + o) * 16384 + ehh * 128 + eww] = v;
    }
}

extern "C" void kernel_launch(void* const* d_in, const int* in_sizes, int n_in,
                              void* d_out, int out_size, void* d_ws, size_t ws_size,
                              hipStream_t stream) {
    const float* x      = (const float*)d_in[0];
    const float* weight = (const float*)d_in[1];
    const float* bias   = (const float*)d_in[2];
    const float* pg_w   = (const float*)d_in[3];
    const float* pg_b   = (const float*)d_in[4];
    float* out = (float*)d_out;

    unsigned short* xbB  = (unsigned short*)d_ws;        // 4*16384*64 bf16 (8.39 MB)
    unsigned short* wtF  = xbB + (size_t)4 * 16384 * 64; // 36,864 bf16 (fragment order)
    unsigned short* pgwF = wtF + 36864;                  // 18,432 bf16 (fragment order)

    k_nhwc<<<2048, 256, 0, stream>>>(x, xbB);
    k_pack_w<<<216, 256, 0, stream>>>(weight, pg_w, wtF, pgwF);
    k_fused<<<1024, 256, 0, stream>>>(xbB, pgwF, pg_b, wtF, bias, out);
}

// Round 13
// 103.753 us; speedup vs baseline: 1.2217x; 1.0106x over previous
//
#include <hip/hip_runtime.h>
#include <math.h>

// B=4, C=64, H=W=128, O=64, K=3, pad=1, stride=1
// Round-13: R12 (green, 104.8us) + ONE delta: tile 8x8 -> 8x16 px, 512 thr = 8 waves,
// wave w = pixel row w. Halo overfetch 2.84x -> 2.03x, LDS 47.2KB -> 3 blk/CU = 24 waves/CU.
// Bodies verbatim from R12; only geometry constants changed (14->20, 65->129, px>>3 -> row=w).
// Known harness floor ~52us (268MB ws re-poison fill @ ~6TB/s + restores) is inside dur_us.
// ws: xb 8.39 MB + wtF + pgwF (~8.5 MB)

typedef __attribute__((ext_vector_type(8))) short short8;   // 8 bf16 (A/B frag)
typedef __attribute__((ext_vector_type(4))) float f32x4;    // C/D frag

__device__ __forceinline__ float b2f(unsigned short h) {
    union { unsigned u; float f; } v; v.u = ((unsigned)h) << 16; return v.f;
}
__device__ __forceinline__ unsigned short f2b(float f) {   // RNE
    union { float f; unsigned u; } v; v.f = f;
    unsigned r = v.u + 0x7FFFu + ((v.u >> 16) & 1u);
    return (unsigned short)(r >> 16);
}

// ---------------- K0: NCHW fp32 -> NHWC bf16 (exact R12) ----------------
__global__ __launch_bounds__(256) void k_nhwc(const float* __restrict__ x,
                                              unsigned short* __restrict__ xb) {
    __shared__ float tile[64][33];
    int bid = blockIdx.x;
    int b = bid >> 9, h = (bid >> 2) & 127, w0 = (bid & 3) * 32;
    int t = threadIdx.x;
    for (int idx = t; idx < 2048; idx += 256) {
        int c = idx >> 5, w = idx & 31;
        tile[c][w] = x[((b * 64 + c) * 128 + h) * 128 + w0 + w];
    }
    __syncthreads();
    {
        int wl = t >> 3, c0 = (t & 7) * 8;
        short8 v;
#pragma unroll
        for (int e = 0; e < 8; ++e) v[e] = (short)f2b(tile[c0 + e][wl]);
        *(short8*)&xb[(((size_t)b * 128 + h) * 128 + w0 + wl) * 64 + c0] = v;
    }
}

// ---------------- K1: pack weights to bf16, FRAGMENT order (exact R12) ----------------
__global__ __launch_bounds__(256) void k_pack_w(const float* __restrict__ weight,
                                                const float* __restrict__ pg_w,
                                                unsigned short* __restrict__ wtF,
                                                unsigned short* __restrict__ pgwF) {
    int idx = blockIdx.x * 256 + threadIdx.x;
    if (idx < 36864) {
        int e = idx & 7, l = (idx >> 3) & 63, grp = idx >> 9;   // grp 0..71
        int nt = grp & 3, kb = (grp >> 2) & 1, kk = grp >> 3;
        int ln = l & 15, quad = l >> 4;
        int o = nt * 16 + ln;
        int c = kb * 32 + quad * 8 + e;
        wtF[idx] = f2b(weight[(o * 64 + c) * 9 + kk]);
    }
    int i2 = idx - 36864;
    if (i2 >= 0 && i2 < 18432) {
        int e = i2 & 7, l = (i2 >> 3) & 63, grp = i2 >> 9;      // grp 0..35
        int tile = grp & 1, kb = grp >> 1;
        int ln = l & 15, quad = l >> 4;
        int p = tile * 16 + ln;
        int k = kb * 32 + quad * 8 + e;
        float v = 0.f;
        if (p < 27) {
            int q = k >> 6, c = k & 63;
            v = pg_w[(p * 64 + c) * 9 + q];
        }
        pgwF[i2] = f2b(v);
    }
}

// ---------------- K2: fused offset-conv + deformable conv, 8x16 tile ----------------
// 512 blocks (b x 16 x 8), tile = 8 rows x 16 cols. 512 threads = 8 waves; wave w = row w.
__global__ __launch_bounds__(512) void k_fused(const unsigned short* __restrict__ xb,
                                               const unsigned short* __restrict__ pgwF,
                                               const float* __restrict__ pg_b,
                                               const unsigned short* __restrict__ wtF,
                                               const float* __restrict__ bias,
                                               float* __restrict__ out) {
    __shared__ unsigned short patch[260 * 64];   // 33.3 KB [pos=yy*20+xx][c ^ (pos&7)*8]
    __shared__ float P_s[27 * 129];              // 13.9 KB [param][px], stride 129

    int bid = blockIdx.x;
    int b  = bid >> 7;
    int h0 = ((bid >> 3) & 15) * 8;
    int w0 = (bid & 7) * 16;
    int t = threadIdx.x;
    int base_y = h0 - 2, base_x = w0 - 2;
    const unsigned short* xbb = xb + (size_t)b * 16384 * 64;

    // ---- phase 0: stage patch from xb; 2080 b128 chunks, coalesced ----
    for (int i = t; i < 2080; i += 512) {
        int yy = i / 160;                 // 8 chunks per 20-col row
        int r  = i - yy * 160;
        int xx = r >> 3;
        int c0 = (r & 7) * 8;
        int gy = base_y + yy, gx = base_x + xx;
        int pos = yy * 20 + xx;
        short8 v = (short8)0;
        if (((unsigned)gy < 128u) && ((unsigned)gx < 128u))
            v = *(const short8*)&xbb[(gy * 128 + gx) * 64 + c0];
        *(short8*)&patch[pos * 64 + (c0 ^ ((pos & 7) * 8))] = v;
    }
    __syncthreads();

    int l = t & 63, w = t >> 6;          // w = 0..7 = pixel row
    int quad = l >> 4, ln = l & 15;
    int px = w * 16 + ln;                // px = row-major pixel id (row w, col ln)
    int hh = h0 + w, ww = w0 + ln;

    // ---- phase 1: offset conv MFMA (M=128, N=32, K=576), B from pgwF coalesced ----
    {
        f32x4 o0 = {0.f, 0.f, 0.f, 0.f}, o1 = {0.f, 0.f, 0.f, 0.f};
#pragma unroll
        for (int kb = 0; kb < 18; ++kb) {
            int q = kb >> 1;
            int kh = q / 3, kw = q - 3 * (q / 3);
            short8 b0 = *(const short8*)&pgwF[(kb * 2 + 0) * 512 + l * 8];   // lane*16B
            short8 b1 = *(const short8*)&pgwF[(kb * 2 + 1) * 512 + l * 8];
            int aoff = (w + kh + 1) * 20 + (ln + kw + 1);
            int c0 = (kb & 1) * 32 + quad * 8;
            short8 af = *(const short8*)&patch[aoff * 64 + (c0 ^ ((aoff & 7) * 8))];
            o0 = __builtin_amdgcn_mfma_f32_16x16x32_bf16(af, b0, o0, 0, 0, 0);
            o1 = __builtin_amdgcn_mfma_f32_16x16x32_bf16(af, b1, o1, 0, 0, 0);
        }
#pragma unroll
        for (int tile = 0; tile < 2; ++tile) {
            int p = tile * 16 + ln;
            f32x4 a = tile ? o1 : o0;
            if (p < 27) {
                float bo = pg_b[p];
#pragma unroll
                for (int i = 0; i < 4; ++i) {
                    int wpx = w * 16 + quad * 4 + i;
                    float v = a[i] + bo;
                    if (p >= 18) v = 1.f / (1.f + expf(-v));
                    P_s[p * 129 + wpx] = v;
                }
            }
        }
    }
    __syncthreads();

    // ---- phase 2: sampling + main GEMM (M=128,N=64,K=576), B from wtF coalesced ----
    f32x4 acc[4];
#pragma unroll
    for (int nt = 0; nt < 4; ++nt) acc[nt] = (f32x4){0.f, 0.f, 0.f, 0.f};

    for (int kk = 0; kk < 9; ++kk) {
        // B fragments: coalesced lane*16B loads (L1/L2-hot)
        short8 bfr[2][4];
#pragma unroll
        for (int kb = 0; kb < 2; ++kb)
#pragma unroll
            for (int nt = 0; nt < 4; ++nt)
                bfr[kb][nt] = *(const short8*)&wtF[((kk * 2 + kb) * 4 + nt) * 512 + l * 8];

        // bilinear params from LDS (R12 body; stride 129)
        int ki = kk / 3, kj = kk - 3 * (kk / 3);
        float dyv = P_s[(2 * kk) * 129 + px];
        float dxv = P_s[(2 * kk + 1) * 129 + px];
        float m   = P_s[(18 + kk) * 129 + px];
        float ys = (float)(hh - 1 + ki) + dyv;
        float xs = (float)(ww - 1 + kj) + dxv;
        float y0f = floorf(ys), x0f = floorf(xs);
        int y0 = (int)y0f, x0 = (int)x0f;
        float ly = ys - y0f, lx = xs - x0f;
        float v0y = ((unsigned)y0 < 128u) ? 1.f : 0.f;
        float v1y = ((unsigned)(y0 + 1) < 128u) ? 1.f : 0.f;
        float v0x = ((unsigned)x0 < 128u) ? 1.f : 0.f;
        float v1x = ((unsigned)(x0 + 1) < 128u) ? 1.f : 0.f;
        float w00 = (1.f - ly) * (1.f - lx) * v0y * v0x * m;
        float w01 = (1.f - ly) * lx * v0y * v1x * m;
        float w10 = ly * (1.f - lx) * v1y * v0x * m;
        float w11 = ly * lx * v1y * v1x * m;
        int ly0 = y0 - base_y, lx0 = x0 - base_x;
        bool inp = ((unsigned)ly0 < 12u) && ((unsigned)lx0 < 18u);

        short8 r[2][4];
        if (inp) {
            int pos = ly0 * 20 + lx0;
#pragma unroll
            for (int kb = 0; kb < 2; ++kb) {
                int c0 = kb * 32 + quad * 8;
                r[kb][0] = *(const short8*)&patch[pos * 64 + (c0 ^ ((pos & 7) * 8))];
                r[kb][1] = *(const short8*)&patch[(pos + 1) * 64 + (c0 ^ (((pos + 1) & 7) * 8))];
                r[kb][2] = *(const short8*)&patch[(pos + 20) * 64 + (c0 ^ (((pos + 20) & 7) * 8))];
                r[kb][3] = *(const short8*)&patch[(pos + 21) * 64 + (c0 ^ (((pos + 21) & 7) * 8))];
            }
        } else {   // rare (|offset| >= 1): direct xb reads, clamped corners
            int y0c = min(max(y0, 0), 127), y1c = min(max(y0 + 1, 0), 127);
            int x0c = min(max(x0, 0), 127), x1c = min(max(x0 + 1, 0), 127);
            int base00 = (y0c * 128 + x0c) * 64;
            int dxo = (x1c - x0c) * 64, dyo = (y1c - y0c) * 8192;
#pragma unroll
            for (int kb = 0; kb < 2; ++kb) {
                int c0 = kb * 32 + quad * 8;
                r[kb][0] = *(const short8*)&xbb[base00 + c0];
                r[kb][1] = *(const short8*)&xbb[base00 + dxo + c0];
                r[kb][2] = *(const short8*)&xbb[base00 + dyo + c0];
                r[kb][3] = *(const short8*)&xbb[base00 + dyo + dxo + c0];
            }
        }

        short8 af[2];
#pragma unroll
        for (int kb = 0; kb < 2; ++kb)
#pragma unroll
            for (int e = 0; e < 8; ++e) {
                float v = w00 * b2f((unsigned short)r[kb][0][e]) + w01 * b2f((unsigned short)r[kb][1][e])
                        + w10 * b2f((unsigned short)r[kb][2][e]) + w11 * b2f((unsigned short)r[kb][3][e]);
                af[kb][e] = (short)f2b(v);
            }

#pragma unroll
        for (int kb = 0; kb < 2; ++kb)
#pragma unroll
            for (int nt = 0; nt < 4; ++nt)
                acc[nt] = __builtin_amdgcn_mfma_f32_16x16x32_bf16(af[kb], bfr[kb][nt], acc[nt], 0, 0, 0);
    }

    // ---- epilogue: lane's 4 D-rows per nt = row w, cols quad*4..+3 -> float4 ----
    int ehh = h0 + w, eww = w0 + quad * 4;
#pragma unroll
    for (int nt = 0; nt < 4; ++nt) {
        int o = nt * 16 + ln;
        float bo = bias[o];
        float4 v;
        v.x = acc[nt][0] + bo; v.y = acc[nt][1] + bo;
        v.z = acc[nt][2] + bo; v.w = acc[nt][3] + bo;
        *(float4*)&out[((size_t)b * 64 + o) * 16384 + ehh * 128 + eww] = v;
    }
}

extern "C" void kernel_launch(void* const* d_in, const int* in_sizes, int n_in,
                              void* d_out, int out_size, void* d_ws, size_t ws_size,
                              hipStream_t stream) {
    const float* x      = (const float*)d_in[0];
    const float* weight = (const float*)d_in[1];
    const float* bias   = (const float*)d_in[2];
    const float* pg_w   = (const float*)d_in[3];
    const float* pg_b   = (const float*)d_in[4];
    float* out = (float*)d_out;

    unsigned short* xbB  = (unsigned short*)d_ws;        // 4*16384*64 bf16 (8.39 MB)
    unsigned short* wtF  = xbB + (size_t)4 * 16384 * 64; // 36,864 bf16 (fragment order)
    unsigned short* pgwF = wtF + 36864;                  // 18,432 bf16 (fragment order)

    k_nhwc<<<2048, 256, 0, stream>>>(x, xbB);
    k_pack_w<<<216, 256, 0, stream>>>(weight, pg_w, wtF, pgwF);
    k_fused<<<512, 512, 0, stream>>>(xbB, pgwF, pg_b, wtF, bias, out);
}